// Round 10
// baseline (665.448 us; speedup 1.0000x reference)
//
#include <hip/hip_runtime.h>
#include <climits>

// ---------------- problem constants (mirror reference) ----------------
constexpr int kB  = 64;
constexpr int kG0 = 19, kG1 = 38, kG2 = 76;
constexpr int kN0 = 3 * kG0 * kG0;   // 1083
constexpr int kN1 = 3 * kG1 * kG1;   // 4332
constexpr int kN2 = 3 * kG2 * kG2;   // 17328
constexpr int kN  = kN0 + kN1 + kN2; // 22743
constexpr int kNP = kN + 1;          // padded row stride (22744): rows 16B-aligned for uint4
constexpr int kM  = 256;             // M_CAND
constexpr int kTopK = 8;
constexpr float kNEG = -1e9f;

// per-image tiles of 256 cells per level: ceil(1083/256)=5, ceil(4332/256)=17, ceil(17328/256)=68
constexpr int kT0 = 5, kT1 = 17, kT2 = 68;
constexpr int kTilesPerImg = kT0 + kT1 + kT2;  // 90
constexpr int kGridScore = 1920;               // pipeline: 1920 blocks x 3 tiles = 5760
constexpr int kTilesPerBlk = 3;

constexpr int kNV4 = kN / 4;         // 5685 full uint4 per image row (covers 22740)
constexpr int kTail = kN - kNV4 * 4; // 3 scalar tail elements

__constant__ float c_anchors[3][3][2] = {
    {{116.f, 90.f}, {156.f, 198.f}, {373.f, 326.f}},
    {{30.f, 61.f},  {62.f, 45.f},   {59.f, 119.f}},
    {{10.f, 13.f},  {16.f, 30.f},   {33.f, 23.f}},
};

// fast transcendentals: v_exp_f32 + v_rcp_f32 (~2-4 ULP; thresholds have huge slack)
__device__ __forceinline__ float fexpf(float x) { return __expf(x); }
__device__ __forceinline__ float frcpf(float x) { return __builtin_amdgcn_rcpf(x); }
__device__ __forceinline__ float fsigm(float x) { return frcpf(1.0f + __expf(-x)); }

// non-temporal 8B load (no cache allocation -> doesn't evict the harness's dirty
// poison lines from L3; confirmed cause of the former ~67us score floor — R9)
__device__ __forceinline__ float2 nt_load_f2(const float2* p) {
  unsigned long long v = __builtin_nontemporal_load((const unsigned long long*)p);
  union { unsigned long long u; float2 f; } c; c.u = v; return c.f;
}

// order-preserving float->uint key (ascending). NEG maps below every score>=0.
__device__ __forceinline__ unsigned score_to_key(float s) {
  unsigned fb = __float_as_uint(s);
  unsigned m = (fb & 0x80000000u) ? 0xFFFFFFFFu : 0x80000000u;
  return fb ^ m;
}
__device__ __forceinline__ float key_to_score(unsigned k) {
  unsigned fb = (k & 0x80000000u) ? (k ^ 0x80000000u) : ~k;
  return __uint_as_float(fb);
}

// flat candidate index n -> cell pointer + (level, anchor, row i, col j, stride)
__device__ __forceinline__ const float* cell_ptr(
    const float* p0, const float* p1, const float* p2, int b, int n,
    int& lvl, int& a, int& gi, int& gj, float& stride) {
  const float* src; int G, m;
  if (n < kN0)            { src = p0; G = kG0; lvl = 0; m = n;             stride = 32.f; }
  else if (n < kN0 + kN1) { src = p1; G = kG1; lvl = 1; m = n - kN0;       stride = 16.f; }
  else                    { src = p2; G = kG2; lvl = 2; m = n - kN0 - kN1; stride = 8.f; }
  int gg = G * G;
  a = m / gg;
  int r = m - a * gg;
  gi = r / G;
  gj = r - gi * G;
  return src + (size_t)((((b * 3 + a) * G + gi) * G + gj)) * 26;
}

// ---------------- wave (64-lane) helpers ----------------
__device__ __forceinline__ void waveArgmax(float& v, int& i) {
  #pragma unroll
  for (int off = 1; off < 64; off <<= 1) {
    float ov = __shfl_xor(v, off);
    int oi = __shfl_xor(i, off);
    if (ov > v || (ov == v && oi < i)) { v = ov; i = oi; }
  }
}
__device__ __forceinline__ float waveMax(float v) {
  #pragma unroll
  for (int off = 1; off < 64; off <<= 1) v = fmaxf(v, __shfl_xor(v, off));
  return v;
}
__device__ __forceinline__ float sel4f(const float a[4], int q) {
  float r = a[0];
  r = (q == 1) ? a[1] : r;
  r = (q == 2) ? a[2] : r;
  r = (q == 3) ? a[3] : r;
  return r;
}
__device__ __forceinline__ int sel4i(const int a[4], int q) {
  int r = a[0];
  r = (q == 1) ? a[1] : r;
  r = (q == 2) ? a[2] : r;
  r = (q == 3) ? a[3] : r;
  return r;
}

// ---------------- parallel threshold-bin finder (256 threads / 4 waves) ----------------
// Largest bin B with suffix_count(B) >= needed; cumAbove = count strictly above B; total = all.
__device__ __forceinline__ void findThresholdBin256(
    const int* hist, int NB, int needed,
    int& outB, int& outCumAbove, int& outTotal,
    int* shWave, int* shOut)
{
  int tid = threadIdx.x, lane = tid & 63, w = tid >> 6;
  if (tid == 0) { shOut[0] = -1; shOut[1] = 0; }
  int ipt = (NB + 255) / 256;
  int base = tid * ipt;
  int csum = 0;
  for (int i = 0; i < ipt; ++i) { int bn = base + i; if (bn < NB) csum += hist[bn]; }
  // inclusive suffix scan within wave (lane l gets sum over lanes >= l)
  int v = csum;
  #pragma unroll
  for (int off = 1; off < 64; off <<= 1) {
    int tv = __shfl_down(v, off);
    if (lane + off < 64) v += tv;
  }
  if (lane == 0) shWave[w] = v;   // wave total
  __syncthreads();
  int above = 0, total = 0;
  #pragma unroll
  for (int q = 0; q < 4; ++q) {
    int wt = shWave[q];
    total += wt;
    if (q > w) above += wt;
  }
  int S = v + above;              // suffix count including own chunk
  if (S >= needed && S - csum < needed) {   // exactly one thread's chunk crosses
    int running = S - csum;
    for (int i = ipt - 1; i >= 0; --i) {
      int bn = base + i; if (bn >= NB) continue;
      int c = hist[bn];
      if (running + c >= needed) { shOut[0] = bn; shOut[1] = running; break; }
      running += c;
    }
  }
  __syncthreads();
  outB = shOut[0]; outCumAbove = shOut[1]; outTotal = total;
  __syncthreads();
}

// ---------------- fused kernel: score (all blocks) + select/NMS (last block per image) ----
// Score: 1920 blocks x 3 tiles, NT staging, double-buffered LDS (R9). After storing its
// tiles a block release-fences + bumps each touched image's done-counter; the block that
// completes a counter (old==89) acquire-fences and runs that image's select+NMS inline —
// overlapped with other blocks' score work. Deadlock-free (no block ever waits).
__global__ __launch_bounds__(256) void fused_kernel(
    const float* __restrict__ p0, const float* __restrict__ p1, const float* __restrict__ p2,
    unsigned* __restrict__ keys, int* __restrict__ done, float* __restrict__ out)
{
  __shared__ float2 smem2[2][256 * 13];   // score stage; aliased by select phase
  __shared__ int shWave[4], shOut[2];
  __shared__ unsigned sT;
  __shared__ int sCgt, sCnt, sEqCnt;
  __shared__ int sFlags[kTilesPerBlk], sNF;

  int t = threadIdx.x;

  // ---- wave-uniform tile parameters for the 3 tiles of this block ----
  const float2* g2[kTilesPerBlk]; int nc[kTilesPerBlk], n0[kTilesPerBlk], bb[kTilesPerBlk];
  #pragma unroll
  for (int j = 0; j < kTilesPerBlk; ++j) {
    int tileId = (int)blockIdx.x + j * kGridScore;
    int b = tileId / kTilesPerImg;
    int r = tileId - b * kTilesPerImg;
    const float* slab; int NL, lvlOff, tile;
    if (r < kT0)            { slab = p0; NL = kN0; lvlOff = 0;         tile = r; }
    else if (r < kT0 + kT1) { slab = p1; NL = kN1; lvlOff = kN0;       tile = r - kT0; }
    else                    { slab = p2; NL = kN2; lvlOff = kN0 + kN1; tile = r - kT0 - kT1; }
    int cellBase = tile * 256;
    nc[j] = min(256, NL - cellBase);
    g2[j] = (const float2*)(slab + ((size_t)b * NL + cellBase) * 26);
    n0[j] = lvlOff + cellBase;
    bb[j] = b;
  }

  // ================= SCORE PHASE (identical math to R9) =================
  {
    float2 nxt[13];
    // prologue: NT-load tile 0 -> regs -> LDS buf 0
    {
      int tot = nc[0] * 13;
      #pragma unroll
      for (int k = 0; k < 13; ++k) {
        int i = t + k * 256;
        if (i < tot) nxt[k] = nt_load_f2(g2[0] + i);
      }
      #pragma unroll
      for (int k = 0; k < 13; ++k) {
        int i = t + k * 256;
        if (i < tot) smem2[0][i] = nxt[k];
      }
    }

    #pragma unroll
    for (int j = 0; j < kTilesPerBlk; ++j) {
      __syncthreads();   // LDS writes of buf j&1 visible; prev compute done

      int totN = 0;
      if (j + 1 < kTilesPerBlk) {        // NT loads for tile j+1 in flight during compute
        totN = nc[j + 1] * 13;
        #pragma unroll
        for (int k = 0; k < 13; ++k) {
          int i = t + k * 256;
          if (i < totN) nxt[k] = nt_load_f2(g2[j + 1] + i);
        }
      }

      int curNc = nc[j], curN0 = n0[j], curB = bb[j];
      const float2* bufp = &smem2[j & 1][0];
      if (t < curNc) {
        const float2* c2 = &bufp[t * 13];   // stride-26-dword: 2-way bank alias (free, m136)
        float2 ol = c2[2];                  // channels 4,5
        float obj = fsigm(ol.x);
        float loc = fsigm(ol.y);
        float tch[20];
        #pragma unroll
        for (int q = 0; q < 10; ++q) { float2 v = c2[3 + q]; tch[2*q] = v.x; tch[2*q+1] = v.y; }
        float lm = tch[0];
        #pragma unroll
        for (int c = 1; c < 20; ++c) lm = fmaxf(lm, tch[c]);
        float se = 0.f;
        #pragma unroll
        for (int c = 0; c < 20; ++c) se += fexpf(tch[c] - lm);
        float cls_conf = frcpf(se);         // max of softmax == exp(0)/sum
        float conf = obj * cls_conf;
        float masked = (obj >= 0.6f && loc >= 0.5f && conf >= 0.05f)
                       ? sqrtf(conf) * sqrtf(loc) : kNEG;  // (obj*cc)^.5 * loc^.5
        keys[(size_t)curB * kNP + curN0 + t] = score_to_key(masked);  // coalesced u32 store
      }

      if (j + 1 < kTilesPerBlk) {         // regs -> other LDS buffer
        float2* dst = &smem2[(j + 1) & 1][0];
        #pragma unroll
        for (int k = 0; k < 13; ++k) {
          int i = t + k * 256;
          if (i < totN) dst[i] = nxt[k];
        }
      }
    }
  }

  // ================= COMPLETION SIGNAL (release) =================
  __syncthreads();     // all threads' key stores issued
  __threadfence();     // device-scope release: L2 writeback -> keys visible cross-XCD
  if (t == 0) {
    int nf = 0;
    #pragma unroll
    for (int j = 0; j < kTilesPerBlk; ++j) {
      int old = atomicAdd(&done[bb[j]], 1);          // device-scope atomic
      if (old == kTilesPerImg - 1) sFlags[nf++] = bb[j];
    }
    sNF = nf;
  }
  __syncthreads();
  int nFlag = sNF;
  if (nFlag == 0) return;

  // LDS aliases for select phase (over the now-dead score stage)
  int* hist = (int*)&smem2[0][0];         // 4096 ints
  int* eqBuf = hist + 4096;               // 1024 ints
  int* ciL = eqBuf + 1024;                // 256 ints
  unsigned* ckL = (unsigned*)(ciL + 256); // 256 u32  (total 22528 B < 53248 B)

  const unsigned keyNEG = score_to_key(kNEG);

  for (int f = 0; f < nFlag; ++f) {
    int b = sFlags[f];
    __threadfence();   // acquire: invalidate caches -> see all producers' key stores
    __syncthreads();

    const unsigned* kk = keys + (size_t)b * kNP;
    const uint4* kk4 = (const uint4*)kk;  // row base b*kNP*4 (16B-aligned)

    // ---- pass 1: top 12 bits (skip NEG keys) ----
    for (int i = t; i < 4096; i += 256) hist[i] = 0;
    __syncthreads();
    for (int x = t; x < kNV4; x += 256) {
      uint4 v = kk4[x];
      if (v.x >= 0x80000000u) atomicAdd(&hist[v.x >> 20], 1);
      if (v.y >= 0x80000000u) atomicAdd(&hist[v.y >> 20], 1);
      if (v.z >= 0x80000000u) atomicAdd(&hist[v.z >> 20], 1);
      if (v.w >= 0x80000000u) atomicAdd(&hist[v.w >> 20], 1);
    }
    if (t < kTail) {
      unsigned k = kk[kNV4 * 4 + t];
      if (k >= 0x80000000u) atomicAdd(&hist[k >> 20], 1);
    }
    __syncthreads();
    int B, cumAbove1, total1;
    findThresholdBin256(hist, 4096, kM, B, cumAbove1, total1, shWave, shOut);

    if (total1 < kM) {
      if (t == 0) { sT = keyNEG; sCgt = total1; }   // fewer than 256 valid
      __syncthreads();
    } else {
      int needed2 = kM - cumAbove1;
      // ---- pass 2: key bits 19:8 within bin B ----
      for (int i = t; i < 4096; i += 256) hist[i] = 0;
      __syncthreads();
      for (int x = t; x < kNV4; x += 256) {
        uint4 v = kk4[x];
        if ((int)(v.x >> 20) == B) atomicAdd(&hist[(v.x >> 8) & 0xFFF], 1);
        if ((int)(v.y >> 20) == B) atomicAdd(&hist[(v.y >> 8) & 0xFFF], 1);
        if ((int)(v.z >> 20) == B) atomicAdd(&hist[(v.z >> 8) & 0xFFF], 1);
        if ((int)(v.w >> 20) == B) atomicAdd(&hist[(v.w >> 8) & 0xFFF], 1);
      }
      if (t < kTail) {
        unsigned k = kk[kNV4 * 4 + t];
        if ((int)(k >> 20) == B) atomicAdd(&hist[(k >> 8) & 0xFFF], 1);
      }
      __syncthreads();
      int B2, cumAbove2, total2;
      findThresholdBin256(hist, 4096, needed2, B2, cumAbove2, total2, shWave, shOut);
      int prefix24 = (B << 12) | B2;
      int needed3 = needed2 - cumAbove2;

      // ---- pass 3: low 8 key bits within 24-bit prefix ----
      for (int i = t; i < 256; i += 256) hist[i] = 0;
      __syncthreads();
      for (int x = t; x < kNV4; x += 256) {
        uint4 v = kk4[x];
        if ((int)(v.x >> 8) == prefix24) atomicAdd(&hist[v.x & 0xFF], 1);
        if ((int)(v.y >> 8) == prefix24) atomicAdd(&hist[v.y & 0xFF], 1);
        if ((int)(v.z >> 8) == prefix24) atomicAdd(&hist[v.z & 0xFF], 1);
        if ((int)(v.w >> 8) == prefix24) atomicAdd(&hist[v.w & 0xFF], 1);
      }
      if (t < kTail) {
        unsigned k = kk[kNV4 * 4 + t];
        if ((int)(k >> 8) == prefix24) atomicAdd(&hist[k & 0xFF], 1);
      }
      __syncthreads();
      int B3, cumAbove3, total3;
      findThresholdBin256(hist, 256, needed3, B3, cumAbove3, total3, shWave, shOut);
      if (t == 0) {
        sT = ((unsigned)prefix24 << 8) | (unsigned)B3;
        sCgt = cumAbove1 + cumAbove2 + cumAbove3;   // exact count of keys > T
      }
      __syncthreads();
    }

    unsigned T = sT;
    int cgt = sCgt;

    // ---- gather into LDS: all keys > T, then fill ties (== T) by smallest index ----
    if (t == 0) { sCnt = 0; sEqCnt = 0; }
    __syncthreads();
    for (int x = t; x < kNV4; x += 256) {
      uint4 v = kk4[x];
      int i4 = x * 4;
      unsigned kv[4] = {v.x, v.y, v.z, v.w};
      #pragma unroll
      for (int e = 0; e < 4; ++e) {
        unsigned k = kv[e];
        if (k > T) {
          int p = atomicAdd(&sCnt, 1);
          ciL[p] = i4 + e; ckL[p] = k;
        } else if (k == T && T != keyNEG) {
          int p = atomicAdd(&sEqCnt, 1); if (p < 1024) eqBuf[p] = i4 + e;
        }
      }
    }
    if (t < kTail) {
      int x = kNV4 * 4 + t;
      unsigned k = kk[x];
      if (k > T) {
        int p = atomicAdd(&sCnt, 1);
        ciL[p] = x; ckL[p] = k;
      } else if (k == T && T != keyNEG) {
        int p = atomicAdd(&sEqCnt, 1); if (p < 1024) eqBuf[p] = x;
      }
    }
    __syncthreads();

    int needed = kM - cgt;  // >= 1 by construction
    if (T == keyNEG) {
      // NEG filler candidates: never kept, never picked, never influence others
      if (t >= cgt && t < kM) { ciL[t] = -1; ckL[t] = keyNEG; }
    } else {
      int ce = min(sEqCnt, 1024);
      if (ce == needed) {               // common case (typically ce == needed == 1)
        if (t < needed) { ciL[cgt + t] = eqBuf[t]; ckL[cgt + t] = T; }
      } else if (t == 0) {              // rare tie overflow: smallest original indices
        for (int q = 0; q < needed; ++q) {
          int mv = INT_MAX, mp = 0;
          for (int x = 0; x < ce; ++x) if (eqBuf[x] < mv) { mv = eqBuf[x]; mp = x; }
          ciL[cgt + q] = mv; ckL[cgt + q] = T; eqBuf[mp] = INT_MAX;
        }
      }
    }
    __syncthreads();

    // ============ NMS: wave 0 only, 4 candidates/lane, register state ============
    if (t < 64) {
      int lane = t;
      float x1[4], y1[4], x2[4], y2[4], val[4], s[4];
      int cls[4];
      bool kept[4];

      #pragma unroll
      for (int q = 0; q < 4; ++q) {
        int slot = q * 64 + lane;
        int n = ciL[slot];
        float sc = key_to_score(ckL[slot]);  // bit-exact score (kNEG for filler)
        kept[q] = false;
        x1[q] = y1[q] = x2[q] = y2[q] = 0.f;
        cls[q] = 0; val[q] = sc; s[q] = sc;
        if (n >= 0) {
          int lvl, a, gi, gj; float stride;
          const float* p = cell_ptr(p0, p1, p2, b, n, lvl, a, gi, gj, stride);
          const float2* r2 = (const float2*)p;   // rows 104 B: even offsets 8B-aligned
          float2 c01 = r2[0], c23 = r2[1];
          float cx = (fsigm(c01.x) + (float)gj) * stride;
          float cy = (fsigm(c01.y) + (float)gi) * stride;
          float w = fexpf(c23.x) * c_anchors[lvl][a][0];  // (exp*anc/str)*str == exp*anc
          float h = fexpf(c23.y) * c_anchors[lvl][a][1];
          x1[q] = fminf(fmaxf(cx - 0.5f * w, 0.f), 608.f);
          y1[q] = fminf(fmaxf(cy - 0.5f * h, 0.f), 608.f);
          x2[q] = fminf(fmaxf(cx + 0.5f * w, 0.f), 608.f);
          y2[q] = fminf(fmaxf(cy + 0.5f * h, 0.f), 608.f);
          float lm = -3.4e38f; int mc = 0;
          #pragma unroll
          for (int j = 3; j < 13; ++j) {
            float2 v = r2[j];
            int c0 = 2 * (j - 3);
            if (v.x > lm) { lm = v.x; mc = c0; }
            if (v.y > lm) { lm = v.y; mc = c0 + 1; }
          }
          cls[q] = mc;
        }
      }

      float top8[8];
      #pragma unroll
      for (int i = 0; i < 8; ++i) top8[i] = kNEG;
      int keptCount = 0;

      for (int it = 0; it < kM; ++it) {
        float bv = s[0]; int bq = 0;
        #pragma unroll
        for (int q = 1; q < 4; ++q) if (s[q] > bv) { bv = s[q]; bq = q; }
        int bi = bq * 64 + lane;
        waveArgmax(bv, bi);
        if (bv < 0.1f) break;   // remaining reference steps are no-ops -> exact

        int wlane = bi & 63, wq = bi >> 6;
        float jx1 = __shfl(sel4f(x1, wq), wlane);
        float jy1 = __shfl(sel4f(y1, wq), wlane);
        float jx2 = __shfl(sel4f(x2, wq), wlane);
        float jy2 = __shfl(sel4f(y2, wq), wlane);
        float jval = __shfl(sel4f(val, wq), wlane);
        int   cj  = __shfl(sel4i(cls, wq), wlane);

        float a1 = (jx2 - jx1 + 1.0f) * (jy2 - jy1 + 1.0f);
        #pragma unroll
        for (int q = 0; q < 4; ++q) {
          if (cls[q] == cj) {
            float ix1 = fmaxf(jx1, x1[q]), iy1 = fmaxf(jy1, y1[q]);
            float ix2 = fminf(jx2, x2[q]), iy2 = fminf(jy2, y2[q]);
            float inter = fmaxf(ix2 - ix1 + 1.0f, 0.0f) * fmaxf(iy2 - iy1 + 1.0f, 0.0f);
            float a2 = (x2[q] - x1[q] + 1.0f) * (y2[q] - y1[q] + 1.0f);
            float iou = inter / (a1 + a2 - inter + 1e-16f);
            s[q] *= fexpf(-(iou * iou) * 2.0f);
          }
          if (bi == q * 64 + lane) { kept[q] = true; s[q] = kNEG; }
        }

        float v = jval;
        #pragma unroll
        for (int i = 0; i < 8; ++i) { float m = fmaxf(top8[i], v); v = fminf(top8[i], v); top8[i] = m; }
        ++keptCount;
        if (keptCount >= kTopK) {
          float am = kNEG;
          #pragma unroll
          for (int q = 0; q < 4; ++q) if (s[q] >= 0.1f) am = fmaxf(am, val[q]);
          am = waveMax(am);
          // s monotone non-increasing, originals fixed, kept never reverts -> exact stop
          if (am < top8[7]) break;
        }
      }

      // keep_top_k by ORIGINAL score among kept
      float fsc[4];
      #pragma unroll
      for (int q = 0; q < 4; ++q) fsc[q] = kept[q] ? val[q] : kNEG;
      for (int k = 0; k < kTopK; ++k) {
        float bv = fsc[0]; int bq = 0;
        #pragma unroll
        for (int q = 1; q < 4; ++q) if (fsc[q] > bv) { bv = fsc[q]; bq = q; }
        int bi = bq * 64 + lane;
        waveArgmax(bv, bi);
        int wlane = bi & 63, wq = bi >> 6;
        if (lane == wlane) {
          float* o = out + (size_t)(b * kTopK + k) * 6;
          if (bv > kNEG * 0.5f) {
            o[0] = sel4f(x1, wq); o[1] = sel4f(y1, wq);
            o[2] = sel4f(x2, wq); o[3] = sel4f(y2, wq);
            o[4] = sel4f(val, wq); o[5] = (float)sel4i(cls, wq);
          } else {
            o[0] = 0.f; o[1] = 0.f; o[2] = 0.f; o[3] = 0.f; o[4] = 0.f; o[5] = 0.f;
          }
        }
        #pragma unroll
        for (int q = 0; q < 4; ++q) if (bi == q * 64 + lane) fsc[q] = kNEG;
      }
    }
    __syncthreads();   // before next flagged image reuses the LDS aliases
  }
}

// ---------------- host launch ----------------
extern "C" void kernel_launch(void* const* d_in, const int* in_sizes, int n_in,
                              void* d_out, int out_size, void* d_ws, size_t ws_size,
                              hipStream_t stream) {
  const float* p0 = (const float*)d_in[0];
  const float* p1 = (const float*)d_in[1];
  const float* p2 = (const float*)d_in[2];
  float* out = (float*)d_out;

  // workspace: keys u32[B*kNP] (5.82 MB, padded rows) | done int[64]
  unsigned* keys = (unsigned*)d_ws;
  int* done = (int*)(keys + (size_t)kB * kNP);

  hipMemsetAsync(done, 0, kB * sizeof(int), stream);   // graph-capture legal
  fused_kernel<<<kGridScore, 256, 0, stream>>>(p0, p1, p2, keys, done, out);
}